// Round 1
// baseline (834.241 us; speedup 1.0000x reference)
//
#include <hip/hip_runtime.h>
#include <hip/hip_bf16.h>
#include <math.h>

// Problem constants
#define NU   256      // NUM_UNITS
#define DH   1024     // DIM_HIDDEN
#define NG   8        // NUM_GROUPS
#define BB   768      // BATCH
#define J1N  (BB/NG)  // 96
#define UC   16       // u-chunk per block in attn kernel

// ---------------------------------------------------------------------------
// Build X2 = [x ; x_masked]  (1536 x 256)
// ---------------------------------------------------------------------------
__global__ __launch_bounds__(256) void build_x2(const float* __restrict__ x,
                                                const int* __restrict__ mask,
                                                float* __restrict__ X2) {
    int idx = blockIdx.x * 256 + threadIdx.x;     // 0 .. 1536*256-1
    int r = idx >> 8;           // /256
    int c = idx & 255;
    if (r < BB) {
        X2[idx] = x[idx];
    } else {
        int src = (r - BB) * NU + c;
        X2[idx] = mask[src] ? 0.0f : x[src];
    }
}

// ---------------------------------------------------------------------------
// fp32 GEMM + bias (+ optional leaky-relu 0.01): C[M,N] = act(A[M,K]@B[K,N]+b)
// 64x64 tile, 256 threads, 4x4 per thread, BK=16
// ---------------------------------------------------------------------------
__global__ __launch_bounds__(256) void gemm_bias(const float* __restrict__ A,
                                                 const float* __restrict__ B,
                                                 const float* __restrict__ bias,
                                                 float* __restrict__ C,
                                                 int M, int N, int K, int leaky) {
    const int BK = 16;
    __shared__ float As[BK][64 + 1];
    __shared__ float Bs[BK][64];
    int t  = threadIdx.x;
    int tx = t & 15;
    int ty = t >> 4;
    int m0 = blockIdx.y * 64;
    int n0 = blockIdx.x * 64;

    float acc[4][4] = {};

    for (int k0 = 0; k0 < K; k0 += BK) {
        // A tile 64x16 (row-major A[M,K]) -> transposed into As[k][m]
        {
            int r = t >> 2;              // 0..63
            int c = (t & 3) * 4;         // 0,4,8,12
            const float4 a = *(const float4*)&A[(size_t)(m0 + r) * K + k0 + c];
            As[c + 0][r] = a.x;
            As[c + 1][r] = a.y;
            As[c + 2][r] = a.z;
            As[c + 3][r] = a.w;
        }
        // B tile 16x64
        {
            int r = t >> 4;              // 0..15
            int c = (t & 15) * 4;        // 0..60
            *(float4*)&Bs[r][c] = *(const float4*)&B[(size_t)(k0 + r) * N + n0 + c];
        }
        __syncthreads();
        #pragma unroll
        for (int k = 0; k < BK; ++k) {
            float a[4], b[4];
            #pragma unroll
            for (int q = 0; q < 4; ++q) a[q] = As[k][ty * 4 + q];
            #pragma unroll
            for (int q = 0; q < 4; ++q) b[q] = Bs[k][tx * 4 + q];
            #pragma unroll
            for (int im = 0; im < 4; ++im)
                #pragma unroll
                for (int in = 0; in < 4; ++in)
                    acc[im][in] = fmaf(a[im], b[in], acc[im][in]);
        }
        __syncthreads();
    }

    #pragma unroll
    for (int im = 0; im < 4; ++im) {
        int m = m0 + ty * 4 + im;
        #pragma unroll
        for (int in = 0; in < 4; ++in) {
            int n = n0 + tx * 4 + in;
            float v = acc[im][in] + bias[n];
            if (leaky) v = v > 0.0f ? v : 0.01f * v;
            C[(size_t)m * N + n] = v;
        }
    }
}

// ---------------------------------------------------------------------------
// Main: per (i, u-chunk) block — logits into LDS, grouped softmax, write out.
// KQ: rows 0..767 = key, rows 768..1535 = query
// ---------------------------------------------------------------------------
__global__ __launch_bounds__(256) void attn_kernel(const float* __restrict__ KQ,
                                                   const float* __restrict__ temp,
                                                   float* __restrict__ out) {
    __shared__ float s[BB * UC];       // 768*16*4 = 48 KB
    __shared__ float s_q[UC];
    __shared__ float s_t[UC];

    const int uc = blockIdx.x;         // 0..15
    const int i  = blockIdx.y;         // 0..767
    const int t  = threadIdx.x;        // 0..255

    const float* key   = KQ;
    const float* query = KQ + (size_t)BB * NU;

    if (t < UC) {
        s_q[t] = query[(size_t)i * NU + uc * UC + t];
        s_t[t] = temp[uc * UC + t];
    }
    __syncthreads();

    // fill logits: s[j*UC + u] = -|key[j,u] - query[i,u]| * temp[u]
    for (int idx = t; idx < BB * UC; idx += 256) {
        int j = idx >> 4;              // /UC
        int u = idx & (UC - 1);
        float kv = key[(size_t)j * NU + uc * UC + u];
        float lg = -fabsf(kv - s_q[u]) * s_t[u];
        if (j == i) lg = -1e30f;       // diagonal -> -inf
        s[idx] = lg;
    }
    __syncthreads();

    // softmax over j1 (stride NG in j) for each (j2, u): 8*16 = 128 groups
    if (t < NG * UC) {
        int j2 = t >> 4;               // /UC
        int u  = t & (UC - 1);
        int base = j2 * UC + u;
        const int stride = NG * UC;    // 128 floats
        float m = -1e30f;
        #pragma unroll 4
        for (int j1 = 0; j1 < J1N; ++j1)
            m = fmaxf(m, s[base + j1 * stride]);
        float sum = 0.0f;
        #pragma unroll 4
        for (int j1 = 0; j1 < J1N; ++j1) {
            float e = __expf(s[base + j1 * stride] - m);
            s[base + j1 * stride] = e;
            sum += e;
        }
        float inv = 0.125f / sum;      // /8 folded in
        #pragma unroll 4
        for (int j1 = 0; j1 < J1N; ++j1)
            s[base + j1 * stride] *= inv;
    }
    __syncthreads();

    // coalesced write-out
    float* o = out + (size_t)i * BB * NU + uc * UC;
    for (int idx = t; idx < BB * UC; idx += 256) {
        int j = idx >> 4;
        int u = idx & (UC - 1);
        o[(size_t)j * NU + u] = s[idx];
    }
}

// ---------------------------------------------------------------------------
// mask -> float epilogue (output 1)
// ---------------------------------------------------------------------------
__global__ __launch_bounds__(256) void mask_out(const int* __restrict__ mask,
                                                float* __restrict__ out) {
    int idx = blockIdx.x * 256 + threadIdx.x;   // 0 .. 768*256-1
    out[idx] = mask[idx] ? 1.0f : 0.0f;
}

// ---------------------------------------------------------------------------
extern "C" void kernel_launch(void* const* d_in, const int* in_sizes, int n_in,
                              void* d_out, int out_size, void* d_ws, size_t ws_size,
                              hipStream_t stream) {
    const float* x    = (const float*)d_in[0];
    const int*   mask = (const int*)d_in[1];
    const float* W1   = (const float*)d_in[2];
    const float* b1   = (const float*)d_in[3];
    const float* W2   = (const float*)d_in[4];
    const float* b2   = (const float*)d_in[5];
    const float* temp = (const float*)d_in[6];
    float* out = (float*)d_out;

    float* ws = (float*)d_ws;
    float* X2 = ws;                                   // 1536*256
    float* H  = X2 + 2 * BB * NU;                     // 1536*1024
    float* KQ = H + 2 * BB * DH;                      // 1536*256

    // 1) X2 = [x ; x_masked]
    build_x2<<<dim3(2 * BB * NU / 256), dim3(256), 0, stream>>>(x, mask, X2);

    // 2) H = leaky_relu(X2 @ W1 + b1)   M=1536 N=1024 K=256
    gemm_bias<<<dim3(DH / 64, 2 * BB / 64), dim3(256), 0, stream>>>(
        X2, W1, b1, H, 2 * BB, DH, NU, 1);

    // 3) KQ = H @ W2 + b2               M=1536 N=256 K=1024
    gemm_bias<<<dim3(NU / 64, 2 * BB / 64), dim3(256), 0, stream>>>(
        H, W2, b2, KQ, 2 * BB, NU, DH, 0);

    // 4) main attention-weight kernel
    attn_kernel<<<dim3(NU / UC, BB), dim3(256), 0, stream>>>(KQ, temp, out);

    // 5) mask as float (output 1)
    mask_out<<<dim3(BB * NU / 256), dim3(256), 0, stream>>>(
        mask, out + (size_t)BB * BB * NU);
}